// Round 6
// baseline (594.419 us; speedup 1.0000x reference)
//
#include <hip/hip_runtime.h>
#include <stdint.h>

// ---------------------------------------------------------------------------
// Net_27891517620298: edge-popup supermask CNN forward.
// R23: LDS path DELETED from conv2/conv3, per R22 ablation:
//   V0(full)=81us, V2(no-A)=80us, V1(no-staging)~30us, V3(no-ds_read)~30us,
//   V4(skeleton)~30us => the global->LDS->reg round-trip is a ~50us
//   super-additive interaction; neither side alone costs anything.
// Fix (catalog Common-mistake #7: don't stage what the caches serve):
//   B-fragments are loaded straight from global NHWC into registers (each
//   lane's 16B frag = one dwordx4; wave = 16 full 64B lines). Reuse (4 waves
//   x ~2.25 taps) is served by L1/L2/L3: per-chunk tile ~37KB (L1-sized),
//   per-image slice ~1MB (L2-sized), whole h1/h2 fit L3. NO __shared__, NO
//   barriers: waves free-run, so VMEM latency is hidden by TLP (the barrier
//   lockstep that defeated R18-R21 is structurally gone). OOB pixels read a
//   16B zero-guard via pointer select (only dy==0 / dx==0 taps need it,
//   compile-time pruned). conv3 grid SWAPYZ: kb-partners 128 apart = same
//   XCD L2. Rest of pipeline = R17 (measured-best).
// ---------------------------------------------------------------------------

typedef __attribute__((ext_vector_type(8))) short short8;
typedef __attribute__((ext_vector_type(4))) short short4v;
typedef __attribute__((ext_vector_type(4))) float floatx4;

__device__ __forceinline__ unsigned short f2bf(float f) {
    unsigned u = __float_as_uint(f);
    u += 0x7fffu + ((u >> 16) & 1u);   // round-to-nearest-even
    return (unsigned short)(u >> 16);
}

// ---------------- exact top-k selection: 3-pass 11/11/9-bit radix -----------
constexpr unsigned CUM0 = 3456u;
constexpr unsigned CUM1 = 298368u;
constexpr unsigned CUM2 = 1478016u;
constexpr unsigned CUM3 = 2002304u;
constexpr unsigned STOT = 2012544u;
constexpr int NBH = 512;

__device__ __forceinline__ int find_tensor(unsigned idx, unsigned& li) {
    if (idx < CUM0) { li = idx;        return 0; }
    if (idx < CUM1) { li = idx - CUM0; return 1; }
    if (idx < CUM2) { li = idx - CUM1; return 2; }
    if (idx < CUM3) { li = idx - CUM2; return 3; }
    li = idx - CUM3; return 4;
}

__global__ __launch_bounds__(256) void hist11(const float* __restrict__ s0,
                                              const float* __restrict__ s1,
                                              const float* __restrict__ s2,
                                              const float* __restrict__ s3,
                                              const float* __restrict__ s4,
                                              const unsigned* __restrict__ P,
                                              unsigned* __restrict__ ghist, int pass) {
    __shared__ unsigned lh[10240];
    const int tid = threadIdx.x;
    const int NB = (pass == 2) ? 512 : 2048;
    for (int i = tid; i < NB * 5; i += 256) lh[i] = 0;
    __syncthreads();

    unsigned pref[5];
    #pragma unroll
    for (int t = 0; t < 5; t++) pref[t] = pass ? P[t] : 0u;
    const int fsh = (pass == 1) ? 20 : 9;

    for (unsigned idx = blockIdx.x * 256u + tid; idx < STOT; idx += NBH * 256u) {
        unsigned li; int t = find_tensor(idx, li);
        const float* sp = t == 0 ? s0 : t == 1 ? s1 : t == 2 ? s2 : t == 3 ? s3 : s4;
        unsigned key = __float_as_uint(sp[li]) & 0x7fffffffu;
        bool ok = (pass == 0) || ((key >> fsh) == pref[t]);
        if (ok) {
            unsigned bin = (pass == 0) ? (key >> 20)
                         : (pass == 1) ? ((key >> 9) & 2047u)
                                       : (key & 511u);
            atomicAdd(&lh[(unsigned)t * NB + bin], 1u);
        }
    }
    __syncthreads();
    const int goff = (pass == 0) ? 0 : (pass == 1) ? 10240 : 20480;
    for (int i = tid; i < NB * 5; i += 256) {
        unsigned v = lh[i];
        if (v) atomicAdd(&ghist[goff + i], v);
    }
}

__global__ __launch_bounds__(256) void find11(const unsigned* __restrict__ ghist,
                                              unsigned* __restrict__ P,
                                              unsigned* __restrict__ targ, int pass) {
    const int t = blockIdx.x;
    const int tid = threadIdx.x;
    const int NB = (pass == 2) ? 512 : 2048;
    const int goff = (pass == 0) ? 0 : (pass == 1) ? 10240 : 20480;
    const int seg = NB / 256;
    __shared__ unsigned bins[2048];
    __shared__ unsigned part[256];
    for (int i = tid; i < NB; i += 256) bins[i] = ghist[goff + t * NB + i];
    __syncthreads();
    unsigned s = 0;
    for (int j = 0; j < seg; j++) s += bins[tid * seg + j];
    part[tid] = s;
    __syncthreads();
    if (tid == 0) {
        unsigned n = t == 0 ? 3456u : t == 1 ? 294912u : t == 2 ? 1179648u
                   : t == 3 ? 524288u : 10240u;
        unsigned target = (pass == 0) ? (n >> 1) : targ[t];
        unsigned cum = 0; int q = 0;
        for (; q < 256; q++) { unsigned c = part[q]; if (cum + c > target) break; cum += c; }
        int b = q * seg;
        for (;; b++) { unsigned c = bins[b]; if (cum + c > target) break; cum += c; }
        targ[t] = target - cum;
        if (pass == 0)      P[t] = (unsigned)b;
        else if (pass == 1) P[t] = (P[t] << 11) | (unsigned)b;
        else                P[t] = (P[t] << 9) | (unsigned)b;
    }
}

__global__ void mask_reorder(const float* __restrict__ w0, const float* __restrict__ w1,
                             const float* __restrict__ w2, const float* __restrict__ w3,
                             const float* __restrict__ w4,
                             const float* __restrict__ s0, const float* __restrict__ s1,
                             const float* __restrict__ s2, const float* __restrict__ s3,
                             const float* __restrict__ s4,
                             const unsigned* __restrict__ T,
                             float* __restrict__ wm1,
                             unsigned short* __restrict__ A2,
                             unsigned short* __restrict__ A3,
                             float* __restrict__ fwm1, float* __restrict__ fwm2,
                             float* __restrict__ pooled) {
    unsigned idx = blockIdx.x * 256u + threadIdx.x;
    if (idx >= STOT) return;
    if (idx < 32768u) pooled[idx] = 0.f;
    unsigned li; int t = find_tensor(idx, li);
    const float* sp = t == 0 ? s0 : t == 1 ? s1 : t == 2 ? s2 : t == 3 ? s3 : s4;
    const float* wp = t == 0 ? w0 : t == 1 ? w1 : t == 2 ? w2 : t == 3 ? w3 : w4;
    unsigned key = __float_as_uint(sp[li]) & 0x7fffffffu;
    float val = (key >= T[t]) ? wp[li] : 0.f;
    if (t == 0) {
        wm1[li] = val;
    } else if (t == 1) {           // w2 [256][128][3][3] -> A2 [e][256][128]
        unsigned k = li / 1152u, r = li - k * 1152u;
        unsigned c = r / 9u, e = r - c * 9u;
        A2[((size_t)e * 256u + k) * 128u + c] = f2bf(val);
    } else if (t == 2) {           // w3 [512][256][3][3] -> A3 [e][512][256]
        unsigned k = li / 2304u, r = li - k * 2304u;
        unsigned c = r / 9u, e = r - c * 9u;
        A3[((size_t)e * 512u + k) * 256u + c] = f2bf(val);
    } else if (t == 3) {
        fwm1[li] = val;
    } else {
        fwm2[li] = val;
    }
}

// ---------------- conv1: direct 3x3 fp32 -> bf16 NHWC -----------------------
template <int C, int H, int W, int K, int TX, int TY, int KT>
__global__ __launch_bounds__(TX* TY) void conv_direct(const float* __restrict__ in,
                                                      const float* __restrict__ wm,
                                                      const float* __restrict__ bias,
                                                      unsigned short* __restrict__ out) {
    constexpr int TILW = TX * 2, TILH = TY * 2;
    constexpr int ITW = TILW + 2, ITH = TILH + 2;
    constexpr int NTHREADS = TX * TY;
    constexpr int NLOAD = (ITH * ITW + NTHREADS - 1) / NTHREADS;
    constexpr int KG = K / KT;

    __shared__ float sIn[ITH * ITW];
    __shared__ float sW[9 * KT];

    const int tid = threadIdx.x;
    const int tx = tid % TX, ty = tid / TX;
    const int kg = blockIdx.z % KG, n = blockIdx.z / KG;
    const int ox0 = blockIdx.x * TILW, oy0 = blockIdx.y * TILH;
    const int ix0 = ox0 - 1, iy0 = oy0 - 1;

    const float* inN = in + (size_t)n * C * H * W;
    const float* wkg = wm + (size_t)kg * KT * C * 9;

    int goff[NLOAD];
    #pragma unroll
    for (int i = 0; i < NLOAD; i++) {
        int idx = tid + i * NTHREADS;
        if (idx < ITH * ITW) {
            int r = idx / ITW, col = idx % ITW;
            int gy = iy0 + r, gx = ix0 + col;
            goff[i] = (gy >= 0 && gy < H && gx >= 0 && gx < W) ? (gy * W + gx) : -1;
        } else goff[i] = -2;
    }

    float acc[2][2][KT];
    #pragma unroll
    for (int py = 0; py < 2; py++)
        #pragma unroll
        for (int px = 0; px < 2; px++)
            #pragma unroll
            for (int j = 0; j < KT; j++) acc[py][px][j] = 0.f;

    for (int c = 0; c < C; c++) {
        const float* inC = inN + (size_t)c * H * W;
        #pragma unroll
        for (int i = 0; i < NLOAD; i++) {
            int g = goff[i];
            if (g >= -1) sIn[tid + i * NTHREADS] = (g >= 0) ? inC[g] : 0.f;
        }
        for (int i = tid; i < 9 * KT; i += NTHREADS) {
            int e = i / KT, j = i % KT;
            sW[i] = wkg[j * C * 9 + c * 9 + e];
        }
        __syncthreads();

        float vin[4][4];
        const float* base = &sIn[(ty * 2) * ITW + tx * 2];
        #pragma unroll
        for (int r = 0; r < 4; r++)
            #pragma unroll
            for (int cc = 0; cc < 4; cc++) vin[r][cc] = base[r * ITW + cc];

        #pragma unroll
        for (int e = 0; e < 9; e++) {
            const int dy = e / 3, dx = e % 3;
            #pragma unroll
            for (int j = 0; j < KT; j++) {
                float wv = sW[e * KT + j];
                #pragma unroll
                for (int py = 0; py < 2; py++)
                    #pragma unroll
                    for (int px = 0; px < 2; px++)
                        acc[py][px][j] = fmaf(vin[py + dy][px + dx], wv, acc[py][px][j]);
            }
        }
        __syncthreads();
    }

    float bj[KT];
    #pragma unroll
    for (int j = 0; j < KT; j++) bj[j] = bias[kg * KT + j];
    #pragma unroll
    for (int py = 0; py < 2; py++)
        #pragma unroll
        for (int px = 0; px < 2; px++) {
            int oy = oy0 + ty * 2 + py, ox = ox0 + tx * 2 + px;
            short8 v;
            #pragma unroll
            for (int j = 0; j < KT; j++) {
                float t = acc[py][px][j] + bj[j];
                v[j] = (short)f2bf(t > 0.f ? t : 0.f);
            }
            *(short8*)(out + ((size_t)(n * H + oy) * W + ox) * K + kg * KT) = v;
        }
}

// ---------------- conv2/conv3: NHWC MFMA, B direct-from-global, no LDS ------
// stride-2 3x3 conv, bf16 NHWC input. Block = 4 waves; tile 128 k x 128 pix.
// Wave: 32 k (2 fm) x 128 pix (8 fn). Per 32-ch chunk x 9 taps: each lane
// loads its B-frag (16B) straight from global; a wave covers 16 full 64B
// lines per load. No __shared__, no barriers - reuse via L1/L2/L3, latency
// via TLP. OOB pixels (top row / left col) select a 16B zero-guard pointer;
// only dy==0 / dx==0 taps pay the select (compile-time pruned).
template <int C, int H, int W, int KOUT, bool POOL, bool SWAPYZ>
__global__ __launch_bounds__(256, 3) void conv_mfma(const unsigned short* __restrict__ in,
                                                    const unsigned short* __restrict__ A,
                                                    const float* __restrict__ bias,
                                                    const unsigned short* __restrict__ zg,
                                                    void* __restrict__ outv) {
    constexpr int OH = H / 2, OW = W / 2;
    constexpr int PR = 128 / OW;          // output rows per 128-pixel tile
    constexpr int FN = 8;                 // B-frags per wave
    constexpr int NC = C / 32;

    const int tid = threadIdx.x;
    const int lane = tid & 63;
    const int wv = tid >> 6;
    const int l15 = lane & 15;
    const int quad = lane >> 4;
    const int pt = blockIdx.x;
    const int kb = SWAPYZ ? blockIdx.z : blockIdx.y;
    const int n  = SWAPYZ ? blockIdx.y : blockIdx.z;
    const int k0 = kb * 128;
    const int oy0 = pt * PR;
    const int g0y = 2 * oy0 - 1;
    const int mw = wv * 32;               // wave's 32 output-channel rows

    // per-fn tap(0,0) base offsets + OOB flags (chunk-invariant)
    int bofs[FN];
    bool rn[FN], cn[FN];
    #pragma unroll
    for (int fn = 0; fn < FN; fn++) {
        int p = fn * 16 + l15;
        int oyl = p / OW, oxl = p % OW;
        int gy = g0y + 2 * oyl;           // row at tap dy=0
        int gx = 2 * oxl - 1;             // col at tap dx=0
        rn[fn] = (gy < 0);
        cn[fn] = (gx < 0);
        bofs[fn] = (gy * W + gx) * C + quad * 8;
    }

    const unsigned short* inN = in + (size_t)n * H * W * C;

    floatx4 acc[2][FN];
    #pragma unroll
    for (int fm = 0; fm < 2; fm++)
        #pragma unroll
        for (int fn = 0; fn < FN; fn++) acc[fm][fn] = (floatx4){0.f, 0.f, 0.f, 0.f};

    const size_t estr = (size_t)KOUT * C;

    #pragma unroll 1
    for (int cc = 0; cc < NC; cc++) {
        const int cof = cc * 32;
        const unsigned short* Abase = A + (size_t)(k0 + mw + l15) * C + cof + quad * 8;

        #pragma unroll
        for (int e = 0; e < 9; e++) {
            const int dy = e / 3, dx = e - dy * 3;
            const int tof = (dy * W + dx) * C;

            short8 a0 = *(const short8*)(Abase + (size_t)e * estr);
            short8 a1 = *(const short8*)(Abase + (size_t)e * estr + 16 * C);

            short8 bfr[FN];
            #pragma unroll
            for (int fn = 0; fn < FN; fn++) {
                const unsigned short* p = inN + bofs[fn] + tof + cof;
                if (dy == 0 || dx == 0) {          // compile-time pruned
                    bool bad = (dy == 0 && rn[fn]) || (dx == 0 && cn[fn]);
                    p = bad ? zg : p;
                }
                bfr[fn] = *(const short8*)p;
            }
            #pragma unroll
            for (int fn = 0; fn < FN; fn++) {
                acc[0][fn] = __builtin_amdgcn_mfma_f32_16x16x32_bf16(a0, bfr[fn], acc[0][fn], 0, 0, 0);
                acc[1][fn] = __builtin_amdgcn_mfma_f32_16x16x32_bf16(a1, bfr[fn], acc[1][fn], 0, 0, 0);
            }
        }
    }

    if (!POOL) {
        unsigned short* out = (unsigned short*)outv;
        #pragma unroll
        for (int fm = 0; fm < 2; fm++) {
            const int k4 = k0 + mw + fm * 16 + quad * 4;
            float b0 = bias[k4], b1 = bias[k4 + 1], b2 = bias[k4 + 2], b3 = bias[k4 + 3];
            #pragma unroll
            for (int fn = 0; fn < FN; fn++) {
                int p = fn * 16 + l15;
                int oy = oy0 + p / OW, ox = p % OW;
                float v0 = acc[fm][fn][0] + b0, v1 = acc[fm][fn][1] + b1;
                float v2 = acc[fm][fn][2] + b2, v3 = acc[fm][fn][3] + b3;
                short4v v;
                v[0] = (short)f2bf(v0 > 0.f ? v0 : 0.f);
                v[1] = (short)f2bf(v1 > 0.f ? v1 : 0.f);
                v[2] = (short)f2bf(v2 > 0.f ? v2 : 0.f);
                v[3] = (short)f2bf(v3 > 0.f ? v3 : 0.f);
                *(short4v*)(out + ((size_t)(n * OH + oy) * OW + ox) * KOUT + k4) = v;
            }
        }
    } else {
        float* out = (float*)outv;
        #pragma unroll
        for (int fm = 0; fm < 2; fm++) {
            #pragma unroll
            for (int reg = 0; reg < 4; reg++) {
                int k = k0 + mw + fm * 16 + quad * 4 + reg;
                float bv = bias[k];
                float s = 0.f;
                #pragma unroll
                for (int fn = 0; fn < FN; fn++) {
                    float v = acc[fm][fn][reg] + bv;
                    s += v > 0.f ? v : 0.f;
                }
                s += __shfl_xor(s, 1); s += __shfl_xor(s, 2);
                s += __shfl_xor(s, 4); s += __shfl_xor(s, 8);
                if (l15 == 0) atomicAdd(&out[n * KOUT + k], s * (1.0f / (OH * OW)));
            }
        }
    }
}

// ---------------- FCs (fp32, tiny; R9 versions) -----------------------------
__global__ void fc1_kernel(const float* __restrict__ pooled, const float* __restrict__ w,
                           const float* __restrict__ b, float* __restrict__ out) {
    int t = blockIdx.x * 256 + threadIdx.x;
    int o = t & 1023, n = t >> 10;
    const float4* w4 = (const float4*)(w + (size_t)o * 512);
    const float4* p4 = (const float4*)(pooled + (size_t)n * 512);
    float acc = 0.f;
    for (int i = 0; i < 128; i++) {
        float4 a = p4[i], ww = w4[i];
        acc += a.x * ww.x + a.y * ww.y + a.z * ww.z + a.w * ww.w;
    }
    acc += b[o];
    out[t] = acc > 0.f ? acc : 0.f;
}

__global__ void fc2_kernel(const float* __restrict__ h, const float* __restrict__ w,
                           const float* __restrict__ b, float* __restrict__ out) {
    int n = blockIdx.x, tid = threadIdx.x;
    __shared__ float redw[40];
    const float4* h4 = (const float4*)(h + (size_t)n * 1024);
    float4 a = h4[tid];
    for (int o = 0; o < 10; o++) {
        const float4* w4 = (const float4*)(w + (size_t)o * 1024);
        float4 ww = w4[tid];
        float v = a.x * ww.x + a.y * ww.y + a.z * ww.z + a.w * ww.w;
        for (int off = 32; off > 0; off >>= 1) v += __shfl_down(v, off);
        if ((tid & 63) == 0) redw[o * 4 + (tid >> 6)] = v;
    }
    __syncthreads();
    if (tid < 10) {
        float s = redw[tid * 4] + redw[tid * 4 + 1] + redw[tid * 4 + 2] + redw[tid * 4 + 3] + b[tid];
        out[n * 10 + tid] = s;
    }
}

extern "C" void kernel_launch(void* const* d_in, const int* in_sizes, int n_in,
                              void* d_out, int out_size, void* d_ws, size_t ws_size,
                              hipStream_t stream) {
    const float* x   = (const float*)d_in[0];
    const float* w1  = (const float*)d_in[1];
    const float* s1  = (const float*)d_in[2];
    const float* b1  = (const float*)d_in[3];
    const float* w2  = (const float*)d_in[4];
    const float* s2  = (const float*)d_in[5];
    const float* b2  = (const float*)d_in[6];
    const float* w3  = (const float*)d_in[7];
    const float* s3  = (const float*)d_in[8];
    const float* b3  = (const float*)d_in[9];
    const float* fw1 = (const float*)d_in[10];
    const float* fs1 = (const float*)d_in[11];
    const float* fb1 = (const float*)d_in[12];
    const float* fw2 = (const float*)d_in[13];
    const float* fs2 = (const float*)d_in[14];
    const float* fb2 = (const float*)d_in[15];
    float* out = (float*)d_out;

    char* ws = (char*)d_ws;
    size_t off = 0;
    auto alloc = [&](size_t bytes) -> char* {
        char* p = ws + off;
        off = (off + bytes + 255) & ~(size_t)255;
        return p;
    };
    unsigned* ghist = (unsigned*)alloc(23040ull * 4);
    unsigned short* zguard = (unsigned short*)alloc(256);  // zeros, after ghist
    unsigned* P     = (unsigned*)alloc(64);
    unsigned* targ  = (unsigned*)alloc(64);
    float* wm1  = (float*)alloc(3456ull * 4);
    float* fwm1 = (float*)alloc(524288ull * 4);
    float* fwm2 = (float*)alloc(10240ull * 4);
    unsigned short* A2 = (unsigned short*)alloc(294912ull * 2);   // bf16 [9][256][128]
    unsigned short* A3 = (unsigned short*)alloc(1179648ull * 2);  // bf16 [9][512][256]
    unsigned short* h1 = (unsigned short*)alloc(33554432ull * 2); // bf16 NHWC 64x64x64x128
    unsigned short* h2 = (unsigned short*)alloc(16777216ull * 2); // bf16 NHWC 64x32x32x256
    float* pooled = (float*)alloc(32768ull * 4);                  // 64x512
    float* fc1h   = (float*)alloc(65536ull * 4);                  // 64x1024
    if (off > ws_size) return;

    // one memset covers ghist (92160 B) + zguard (256 B) - contiguous
    (void)hipMemsetAsync(ghist, 0, 23040ull * 4 + 256, stream);

    for (int pass = 0; pass < 3; pass++) {
        hist11<<<NBH, 256, 0, stream>>>(s1, s2, s3, fs1, fs2, P, ghist, pass);
        find11<<<5, 256, 0, stream>>>(ghist, P, targ, pass);
    }
    int gs = (STOT + 255) / 256;
    mask_reorder<<<gs, 256, 0, stream>>>(w1, w2, w3, fw1, fw2, s1, s2, s3, fs1, fs2, P,
                                         wm1, A2, A3, fwm1, fwm2, pooled);

    // conv1: 3->128, 64x64, stride 1, direct fp32 -> bf16 NHWC h1
    conv_direct<3, 64, 64, 128, 16, 16, 8>
        <<<dim3(2, 2, 64 * 16), 256, 0, stream>>>(x, wm1, b1, h1);
    // conv2: 128->256, 64x64 -> 32x32 NHWC. 8 pixel tiles x 2 k tiles x 64 n
    // (kb-partners 8 apart in linear id -> same XCD)
    conv_mfma<128, 64, 64, 256, false, false>
        <<<dim3(8, 2, 64), 256, 0, stream>>>(h1, A2, b2, zguard, h2);
    // conv3: 256->512, 32x32 -> 16x16, fused GAP. 2 pixel tiles x 64 n x 4 k
    // (SWAPYZ: kb-partners 128 apart in linear id -> same XCD)
    conv_mfma<256, 32, 32, 512, true, true>
        <<<dim3(2, 64, 4), 256, 0, stream>>>(h2, A3, b3, zguard, pooled);

    fc1_kernel<<<256, 256, 0, stream>>>(pooled, fwm1, fb1, fc1h);
    fc2_kernel<<<64, 256, 0, stream>>>(fc1h, fwm2, fb2, out);
}

// Round 7
// 444.317 us; speedup vs baseline: 1.3378x; 1.3378x over previous
//
#include <hip/hip_runtime.h>
#include <stdint.h>

// ---------------------------------------------------------------------------
// Net_27891517620298: edge-popup supermask CNN forward.
// R24: conv2/conv3 = R17 tap structure + double-buffered async staging.
// R22 ablation: stage-only ~30us, taps-only ~30us, both = 81us (serialized).
// R23 (no LDS at all) = 185us: caches do NOT serve the 9-tap reuse; LDS is
// required. So overlap the two phases INSIDE the block (T3 minimal 2-phase):
//   - staging via __builtin_amdgcn_global_load_lds (scheduler-proof, no VGPR
//     round trip), double-buffered; 5 slots/pixel so the linear lane-order
//     dest reproduces the PSTR=40 layout EXACTLY (slot 4 = pad, never read;
//     pad/OOB lanes stage from the 16B zero-guard). Tap-read addresses are
//     bit-identical to R17 (same banks, ~1.16M conflicts, known-OK).
//   - per chunk: STAGE(next) -> A-loads + 9 taps (ds_read+MFMA) ->
//     s_waitcnt vmcnt(0) (drains under the taps) -> raw s_barrier.
//     One barrier/chunk; no __syncthreads (its forced early drain was the
//     R17-R20 critical path).
//   - NPIX=64 tiles: LDS 57344 (conv2, 2 blk/CU) / 49152 (conv3, 3 blk/CU).
// ---------------------------------------------------------------------------

typedef __attribute__((ext_vector_type(8))) short short8;
typedef __attribute__((ext_vector_type(4))) short short4v;
typedef __attribute__((ext_vector_type(4))) float floatx4;

__device__ __forceinline__ unsigned short f2bf(float f) {
    unsigned u = __float_as_uint(f);
    u += 0x7fffu + ((u >> 16) & 1u);   // round-to-nearest-even
    return (unsigned short)(u >> 16);
}

// async global->LDS DMA, 16B/lane; LDS dest = wave-uniform base + lane*16
__device__ __forceinline__ void stage16(const unsigned short* g, unsigned short* l) {
    __builtin_amdgcn_global_load_lds(
        (const __attribute__((address_space(1))) unsigned int*)(const void*)g,
        (__attribute__((address_space(3))) unsigned int*)(void*)l,
        16, 0, 0);
}

// ---------------- exact top-k selection: 3-pass 11/11/9-bit radix -----------
constexpr unsigned CUM0 = 3456u;
constexpr unsigned CUM1 = 298368u;
constexpr unsigned CUM2 = 1478016u;
constexpr unsigned CUM3 = 2002304u;
constexpr unsigned STOT = 2012544u;
constexpr int NBH = 512;

__device__ __forceinline__ int find_tensor(unsigned idx, unsigned& li) {
    if (idx < CUM0) { li = idx;        return 0; }
    if (idx < CUM1) { li = idx - CUM0; return 1; }
    if (idx < CUM2) { li = idx - CUM1; return 2; }
    if (idx < CUM3) { li = idx - CUM2; return 3; }
    li = idx - CUM3; return 4;
}

__global__ __launch_bounds__(256) void hist11(const float* __restrict__ s0,
                                              const float* __restrict__ s1,
                                              const float* __restrict__ s2,
                                              const float* __restrict__ s3,
                                              const float* __restrict__ s4,
                                              const unsigned* __restrict__ P,
                                              unsigned* __restrict__ ghist, int pass) {
    __shared__ unsigned lh[10240];
    const int tid = threadIdx.x;
    const int NB = (pass == 2) ? 512 : 2048;
    for (int i = tid; i < NB * 5; i += 256) lh[i] = 0;
    __syncthreads();

    unsigned pref[5];
    #pragma unroll
    for (int t = 0; t < 5; t++) pref[t] = pass ? P[t] : 0u;
    const int fsh = (pass == 1) ? 20 : 9;

    for (unsigned idx = blockIdx.x * 256u + tid; idx < STOT; idx += NBH * 256u) {
        unsigned li; int t = find_tensor(idx, li);
        const float* sp = t == 0 ? s0 : t == 1 ? s1 : t == 2 ? s2 : t == 3 ? s3 : s4;
        unsigned key = __float_as_uint(sp[li]) & 0x7fffffffu;
        bool ok = (pass == 0) || ((key >> fsh) == pref[t]);
        if (ok) {
            unsigned bin = (pass == 0) ? (key >> 20)
                         : (pass == 1) ? ((key >> 9) & 2047u)
                                       : (key & 511u);
            atomicAdd(&lh[(unsigned)t * NB + bin], 1u);
        }
    }
    __syncthreads();
    const int goff = (pass == 0) ? 0 : (pass == 1) ? 10240 : 20480;
    for (int i = tid; i < NB * 5; i += 256) {
        unsigned v = lh[i];
        if (v) atomicAdd(&ghist[goff + i], v);
    }
}

__global__ __launch_bounds__(256) void find11(const unsigned* __restrict__ ghist,
                                              unsigned* __restrict__ P,
                                              unsigned* __restrict__ targ, int pass) {
    const int t = blockIdx.x;
    const int tid = threadIdx.x;
    const int NB = (pass == 2) ? 512 : 2048;
    const int goff = (pass == 0) ? 0 : (pass == 1) ? 10240 : 20480;
    const int seg = NB / 256;
    __shared__ unsigned bins[2048];
    __shared__ unsigned part[256];
    for (int i = tid; i < NB; i += 256) bins[i] = ghist[goff + t * NB + i];
    __syncthreads();
    unsigned s = 0;
    for (int j = 0; j < seg; j++) s += bins[tid * seg + j];
    part[tid] = s;
    __syncthreads();
    if (tid == 0) {
        unsigned n = t == 0 ? 3456u : t == 1 ? 294912u : t == 2 ? 1179648u
                   : t == 3 ? 524288u : 10240u;
        unsigned target = (pass == 0) ? (n >> 1) : targ[t];
        unsigned cum = 0; int q = 0;
        for (; q < 256; q++) { unsigned c = part[q]; if (cum + c > target) break; cum += c; }
        int b = q * seg;
        for (;; b++) { unsigned c = bins[b]; if (cum + c > target) break; cum += c; }
        targ[t] = target - cum;
        if (pass == 0)      P[t] = (unsigned)b;
        else if (pass == 1) P[t] = (P[t] << 11) | (unsigned)b;
        else                P[t] = (P[t] << 9) | (unsigned)b;
    }
}

__global__ void mask_reorder(const float* __restrict__ w0, const float* __restrict__ w1,
                             const float* __restrict__ w2, const float* __restrict__ w3,
                             const float* __restrict__ w4,
                             const float* __restrict__ s0, const float* __restrict__ s1,
                             const float* __restrict__ s2, const float* __restrict__ s3,
                             const float* __restrict__ s4,
                             const unsigned* __restrict__ T,
                             float* __restrict__ wm1,
                             unsigned short* __restrict__ A2,
                             unsigned short* __restrict__ A3,
                             float* __restrict__ fwm1, float* __restrict__ fwm2,
                             float* __restrict__ pooled) {
    unsigned idx = blockIdx.x * 256u + threadIdx.x;
    if (idx >= STOT) return;
    if (idx < 32768u) pooled[idx] = 0.f;
    unsigned li; int t = find_tensor(idx, li);
    const float* sp = t == 0 ? s0 : t == 1 ? s1 : t == 2 ? s2 : t == 3 ? s3 : s4;
    const float* wp = t == 0 ? w0 : t == 1 ? w1 : t == 2 ? w2 : t == 3 ? w3 : w4;
    unsigned key = __float_as_uint(sp[li]) & 0x7fffffffu;
    float val = (key >= T[t]) ? wp[li] : 0.f;
    if (t == 0) {
        wm1[li] = val;
    } else if (t == 1) {           // w2 [256][128][3][3] -> A2 [e][256][128]
        unsigned k = li / 1152u, r = li - k * 1152u;
        unsigned c = r / 9u, e = r - c * 9u;
        A2[((size_t)e * 256u + k) * 128u + c] = f2bf(val);
    } else if (t == 2) {           // w3 [512][256][3][3] -> A3 [e][512][256]
        unsigned k = li / 2304u, r = li - k * 2304u;
        unsigned c = r / 9u, e = r - c * 9u;
        A3[((size_t)e * 512u + k) * 256u + c] = f2bf(val);
    } else if (t == 3) {
        fwm1[li] = val;
    } else {
        fwm2[li] = val;
    }
}

// ---------------- conv1: direct 3x3 fp32 -> bf16 NHWC -----------------------
template <int C, int H, int W, int K, int TX, int TY, int KT>
__global__ __launch_bounds__(TX* TY) void conv_direct(const float* __restrict__ in,
                                                      const float* __restrict__ wm,
                                                      const float* __restrict__ bias,
                                                      unsigned short* __restrict__ out) {
    constexpr int TILW = TX * 2, TILH = TY * 2;
    constexpr int ITW = TILW + 2, ITH = TILH + 2;
    constexpr int NTHREADS = TX * TY;
    constexpr int NLOAD = (ITH * ITW + NTHREADS - 1) / NTHREADS;
    constexpr int KG = K / KT;

    __shared__ float sIn[ITH * ITW];
    __shared__ float sW[9 * KT];

    const int tid = threadIdx.x;
    const int tx = tid % TX, ty = tid / TX;
    const int kg = blockIdx.z % KG, n = blockIdx.z / KG;
    const int ox0 = blockIdx.x * TILW, oy0 = blockIdx.y * TILH;
    const int ix0 = ox0 - 1, iy0 = oy0 - 1;

    const float* inN = in + (size_t)n * C * H * W;
    const float* wkg = wm + (size_t)kg * KT * C * 9;

    int goff[NLOAD];
    #pragma unroll
    for (int i = 0; i < NLOAD; i++) {
        int idx = tid + i * NTHREADS;
        if (idx < ITH * ITW) {
            int r = idx / ITW, col = idx % ITW;
            int gy = iy0 + r, gx = ix0 + col;
            goff[i] = (gy >= 0 && gy < H && gx >= 0 && gx < W) ? (gy * W + gx) : -1;
        } else goff[i] = -2;
    }

    float acc[2][2][KT];
    #pragma unroll
    for (int py = 0; py < 2; py++)
        #pragma unroll
        for (int px = 0; px < 2; px++)
            #pragma unroll
            for (int j = 0; j < KT; j++) acc[py][px][j] = 0.f;

    for (int c = 0; c < C; c++) {
        const float* inC = inN + (size_t)c * H * W;
        #pragma unroll
        for (int i = 0; i < NLOAD; i++) {
            int g = goff[i];
            if (g >= -1) sIn[tid + i * NTHREADS] = (g >= 0) ? inC[g] : 0.f;
        }
        for (int i = tid; i < 9 * KT; i += NTHREADS) {
            int e = i / KT, j = i % KT;
            sW[i] = wkg[j * C * 9 + c * 9 + e];
        }
        __syncthreads();

        float vin[4][4];
        const float* base = &sIn[(ty * 2) * ITW + tx * 2];
        #pragma unroll
        for (int r = 0; r < 4; r++)
            #pragma unroll
            for (int cc = 0; cc < 4; cc++) vin[r][cc] = base[r * ITW + cc];

        #pragma unroll
        for (int e = 0; e < 9; e++) {
            const int dy = e / 3, dx = e % 3;
            #pragma unroll
            for (int j = 0; j < KT; j++) {
                float wv = sW[e * KT + j];
                #pragma unroll
                for (int py = 0; py < 2; py++)
                    #pragma unroll
                    for (int px = 0; px < 2; px++)
                        acc[py][px][j] = fmaf(vin[py + dy][px + dx], wv, acc[py][px][j]);
            }
        }
        __syncthreads();
    }

    float bj[KT];
    #pragma unroll
    for (int j = 0; j < KT; j++) bj[j] = bias[kg * KT + j];
    #pragma unroll
    for (int py = 0; py < 2; py++)
        #pragma unroll
        for (int px = 0; px < 2; px++) {
            int oy = oy0 + ty * 2 + py, ox = ox0 + tx * 2 + px;
            short8 v;
            #pragma unroll
            for (int j = 0; j < KT; j++) {
                float t = acc[py][px][j] + bj[j];
                v[j] = (short)f2bf(t > 0.f ? t : 0.f);
            }
            *(short8*)(out + ((size_t)(n * H + oy) * W + ox) * K + kg * KT) = v;
        }
}

// ---------------- conv2/conv3: NHWC MFMA, dbuf async-staged B in LDS --------
// stride-2 3x3 conv, bf16 NHWC input. Block = 4 waves; tile 128k x NPIX pix.
// LDS layout per buffer: pixel p -> slots [p*5 .. p*5+4], 16B each; slots
// 0-3 = channels (quad*8), slot 4 = pad (never read). Linear slot order is
// exactly what global_load_lds writes; tap reads use p*40 + quad*8 shorts,
// bit-identical to R17's PSTR=40 addressing (same bank behavior).
template <int C, int H, int W, int KOUT, int NPIX, bool POOL, bool SWAPYZ>
__global__ __launch_bounds__(256, 2) void conv_mfma(const unsigned short* __restrict__ in,
                                                    const unsigned short* __restrict__ A,
                                                    const float* __restrict__ bias,
                                                    const unsigned short* __restrict__ zg,
                                                    void* __restrict__ outv) {
    constexpr int OH = H / 2, OW = W / 2;
    constexpr int PR = NPIX / OW;          // output rows per pixel tile
    constexpr int FN = NPIX / 16;          // B-frags per wave
    constexpr int RH = 2 * PR + 1;         // input rows needed
    constexpr int IW = W + 1;              // input cols needed
    constexpr int NC = C / 32;
    constexpr int NPT = RH * IW;           // tile pixels
    constexpr int NSLOT = NPT * 5;         // 5 16B-slots per pixel (4 + pad)
    constexpr int SLMAX = (NSLOT + 255) / 256;
    constexpr int SLOTS = SLMAX * 256;     // padded slot count

    __shared__ unsigned short sIn[2][SLOTS * 8];

    const int tid = threadIdx.x;
    const int lane = tid & 63;
    const int wv = tid >> 6;
    const int l15 = lane & 15;
    const int quad = lane >> 4;
    const int pt = blockIdx.x;
    const int kb = SWAPYZ ? blockIdx.z : blockIdx.y;
    const int n  = SWAPYZ ? blockIdx.y : blockIdx.z;
    const int k0 = kb * 128;
    const int oy0 = pt * PR;
    const int g0y = 2 * oy0 - 1;
    const int mw = wv * 32;                // wave's 32 output-channel rows

    // staging source table (chunk-invariant): slot s = tid + i*256 ->
    // pixel s/5, sub-slot s%5; sub-slot 4 and OOB pixels stage from zguard.
    int goff[SLMAX];
    #pragma unroll
    for (int i = 0; i < SLMAX; i++) {
        int s = tid + i * 256;
        int pix = s / 5, q = s - pix * 5;
        int iy = pix / IW, ix = pix - iy * IW;
        int gy = g0y + iy, gx = ix - 1;
        bool ok = (s < NSLOT) && (q < 4) && (gy >= 0) && (gy < H) && (gx >= 0);
        goff[i] = ok ? ((gy * W + gx) * C + q * 8) : -1;
    }

    // B-frag pixel bases (shorts): identical to R17 PSTR=40 addressing
    int pB[FN];
    #pragma unroll
    for (int fn = 0; fn < FN; fn++) {
        int p = fn * 16 + l15;
        int oyl = p / OW, oxl = p % OW;
        pB[fn] = (oyl * 2 * IW + oxl * 2) * 40 + quad * 8;
    }

    const unsigned short* inN = in + (size_t)n * H * W * C;

    floatx4 acc[2][FN];
    #pragma unroll
    for (int fm = 0; fm < 2; fm++)
        #pragma unroll
        for (int fn = 0; fn < FN; fn++) acc[fm][fn] = (floatx4){0.f, 0.f, 0.f, 0.f};

    const size_t estr = (size_t)KOUT * C;
    const int wvb = tid & 192;             // wave-uniform lane-0 slot offset

    auto stage_chunk = [&](int buf, int cc) {
        const int cof = cc * 32;
        #pragma unroll
        for (int i = 0; i < SLMAX; i++) {
            const unsigned short* src = (goff[i] >= 0) ? (inN + goff[i] + cof) : zg;
            stage16(src, &sIn[buf][(size_t)(i * 256 + wvb) * 8]);
        }
    };

    // prologue: chunk 0 staged and drained once
    stage_chunk(0, 0);
    asm volatile("s_waitcnt vmcnt(0)" ::: "memory");
    __builtin_amdgcn_s_barrier();
    __builtin_amdgcn_sched_barrier(0);

    #pragma unroll 1
    for (int cc = 0; cc < NC; cc++) {
        const int cur = cc & 1;
        const unsigned short* sb = &sIn[cur][0];

        if (cc + 1 < NC) stage_chunk(cur ^ 1, cc + 1);   // async, drains under taps

        // A-frag base: A[e][k0+mw+l15+fm*16][cof+quad*8]; 1-tap-ahead prefetch
        const unsigned short* Abase = A + (size_t)(k0 + mw + l15) * C + cc * 32 + quad * 8;
        short8 a0 = *(const short8*)(Abase);
        short8 a1 = *(const short8*)(Abase + 16 * C);

        #pragma unroll 1
        for (int e = 0; e < 9; e++) {
            short8 ac0 = a0, ac1 = a1;
            if (e < 8) {
                a0 = *(const short8*)(Abase + (size_t)(e + 1) * estr);
                a1 = *(const short8*)(Abase + (size_t)(e + 1) * estr + 16 * C);
            }
            const int dy = e / 3, dx = e - dy * 3;
            const int boff = (dy * IW + dx) * 40;
            short8 bfr[FN];
            #pragma unroll
            for (int fn = 0; fn < FN; fn++)
                bfr[fn] = *(const short8*)(sb + pB[fn] + boff);
            #pragma unroll
            for (int fn = 0; fn < FN; fn++) {
                acc[0][fn] = __builtin_amdgcn_mfma_f32_16x16x32_bf16(ac0, bfr[fn], acc[0][fn], 0, 0, 0);
                acc[1][fn] = __builtin_amdgcn_mfma_f32_16x16x32_bf16(ac1, bfr[fn], acc[1][fn], 0, 0, 0);
            }
        }

        // next chunk's stage has drained under the taps; sync buffers
        asm volatile("s_waitcnt vmcnt(0)" ::: "memory");
        __builtin_amdgcn_s_barrier();
        __builtin_amdgcn_sched_barrier(0);
    }

    if (!POOL) {
        unsigned short* out = (unsigned short*)outv;
        #pragma unroll
        for (int fm = 0; fm < 2; fm++) {
            const int k4 = k0 + mw + fm * 16 + quad * 4;
            float b0 = bias[k4], b1 = bias[k4 + 1], b2 = bias[k4 + 2], b3 = bias[k4 + 3];
            #pragma unroll
            for (int fn = 0; fn < FN; fn++) {
                int p = fn * 16 + l15;
                int oy = oy0 + p / OW, ox = p % OW;
                float v0 = acc[fm][fn][0] + b0, v1 = acc[fm][fn][1] + b1;
                float v2 = acc[fm][fn][2] + b2, v3 = acc[fm][fn][3] + b3;
                short4v v;
                v[0] = (short)f2bf(v0 > 0.f ? v0 : 0.f);
                v[1] = (short)f2bf(v1 > 0.f ? v1 : 0.f);
                v[2] = (short)f2bf(v2 > 0.f ? v2 : 0.f);
                v[3] = (short)f2bf(v3 > 0.f ? v3 : 0.f);
                *(short4v*)(out + ((size_t)(n * OH + oy) * OW + ox) * KOUT + k4) = v;
            }
        }
    } else {
        float* out = (float*)outv;
        #pragma unroll
        for (int fm = 0; fm < 2; fm++) {
            #pragma unroll
            for (int reg = 0; reg < 4; reg++) {
                int k = k0 + mw + fm * 16 + quad * 4 + reg;
                float bv = bias[k];
                float s = 0.f;
                #pragma unroll
                for (int fn = 0; fn < FN; fn++) {
                    float v = acc[fm][fn][reg] + bv;
                    s += v > 0.f ? v : 0.f;
                }
                s += __shfl_xor(s, 1); s += __shfl_xor(s, 2);
                s += __shfl_xor(s, 4); s += __shfl_xor(s, 8);
                if (l15 == 0) atomicAdd(&out[n * KOUT + k], s * (1.0f / (OH * OW)));
            }
        }
    }
}

// ---------------- FCs (fp32, tiny; R9 versions) -----------------------------
__global__ void fc1_kernel(const float* __restrict__ pooled, const float* __restrict__ w,
                           const float* __restrict__ b, float* __restrict__ out) {
    int t = blockIdx.x * 256 + threadIdx.x;
    int o = t & 1023, n = t >> 10;
    const float4* w4 = (const float4*)(w + (size_t)o * 512);
    const float4* p4 = (const float4*)(pooled + (size_t)n * 512);
    float acc = 0.f;
    for (int i = 0; i < 128; i++) {
        float4 a = p4[i], ww = w4[i];
        acc += a.x * ww.x + a.y * ww.y + a.z * ww.z + a.w * ww.w;
    }
    acc += b[o];
    out[t] = acc > 0.f ? acc : 0.f;
}

__global__ void fc2_kernel(const float* __restrict__ h, const float* __restrict__ w,
                           const float* __restrict__ b, float* __restrict__ out) {
    int n = blockIdx.x, tid = threadIdx.x;
    __shared__ float redw[40];
    const float4* h4 = (const float4*)(h + (size_t)n * 1024);
    float4 a = h4[tid];
    for (int o = 0; o < 10; o++) {
        const float4* w4 = (const float4*)(w + (size_t)o * 1024);
        float4 ww = w4[tid];
        float v = a.x * ww.x + a.y * ww.y + a.z * ww.z + a.w * ww.w;
        for (int off = 32; off > 0; off >>= 1) v += __shfl_down(v, off);
        if ((tid & 63) == 0) redw[o * 4 + (tid >> 6)] = v;
    }
    __syncthreads();
    if (tid < 10) {
        float s = redw[tid * 4] + redw[tid * 4 + 1] + redw[tid * 4 + 2] + redw[tid * 4 + 3] + b[tid];
        out[n * 10 + tid] = s;
    }
}

extern "C" void kernel_launch(void* const* d_in, const int* in_sizes, int n_in,
                              void* d_out, int out_size, void* d_ws, size_t ws_size,
                              hipStream_t stream) {
    const float* x   = (const float*)d_in[0];
    const float* w1  = (const float*)d_in[1];
    const float* s1  = (const float*)d_in[2];
    const float* b1  = (const float*)d_in[3];
    const float* w2  = (const float*)d_in[4];
    const float* s2  = (const float*)d_in[5];
    const float* b2  = (const float*)d_in[6];
    const float* w3  = (const float*)d_in[7];
    const float* s3  = (const float*)d_in[8];
    const float* b3  = (const float*)d_in[9];
    const float* fw1 = (const float*)d_in[10];
    const float* fs1 = (const float*)d_in[11];
    const float* fb1 = (const float*)d_in[12];
    const float* fw2 = (const float*)d_in[13];
    const float* fs2 = (const float*)d_in[14];
    const float* fb2 = (const float*)d_in[15];
    float* out = (float*)d_out;

    char* ws = (char*)d_ws;
    size_t off = 0;
    auto alloc = [&](size_t bytes) -> char* {
        char* p = ws + off;
        off = (off + bytes + 255) & ~(size_t)255;
        return p;
    };
    unsigned* ghist = (unsigned*)alloc(23040ull * 4);
    unsigned short* zguard = (unsigned short*)alloc(256);  // zeros, after ghist
    unsigned* P     = (unsigned*)alloc(64);
    unsigned* targ  = (unsigned*)alloc(64);
    float* wm1  = (float*)alloc(3456ull * 4);
    float* fwm1 = (float*)alloc(524288ull * 4);
    float* fwm2 = (float*)alloc(10240ull * 4);
    unsigned short* A2 = (unsigned short*)alloc(294912ull * 2);   // bf16 [9][256][128]
    unsigned short* A3 = (unsigned short*)alloc(1179648ull * 2);  // bf16 [9][512][256]
    unsigned short* h1 = (unsigned short*)alloc(33554432ull * 2); // bf16 NHWC 64x64x64x128
    unsigned short* h2 = (unsigned short*)alloc(16777216ull * 2); // bf16 NHWC 64x32x32x256
    float* pooled = (float*)alloc(32768ull * 4);                  // 64x512
    float* fc1h   = (float*)alloc(65536ull * 4);                  // 64x1024
    if (off > ws_size) return;

    // one memset covers ghist (92160 B) + zguard (256 B) - contiguous
    (void)hipMemsetAsync(ghist, 0, 23040ull * 4 + 256, stream);

    for (int pass = 0; pass < 3; pass++) {
        hist11<<<NBH, 256, 0, stream>>>(s1, s2, s3, fs1, fs2, P, ghist, pass);
        find11<<<5, 256, 0, stream>>>(ghist, P, targ, pass);
    }
    int gs = (STOT + 255) / 256;
    mask_reorder<<<gs, 256, 0, stream>>>(w1, w2, w3, fw1, fw2, s1, s2, s3, fs1, fs2, P,
                                         wm1, A2, A3, fwm1, fwm2, pooled);

    // conv1: 3->128, 64x64, stride 1, direct fp32 -> bf16 NHWC h1
    conv_direct<3, 64, 64, 128, 16, 16, 8>
        <<<dim3(2, 2, 64 * 16), 256, 0, stream>>>(x, wm1, b1, h1);
    // conv2: 128->256, 64x64 -> 32x32 NHWC. 16 pixel tiles x 2 k tiles x 64 n
    // (kb-partners 16 apart in linear id -> same XCD)
    conv_mfma<128, 64, 64, 256, 64, false, false>
        <<<dim3(16, 2, 64), 256, 0, stream>>>(h1, A2, b2, zguard, h2);
    // conv3: 256->512, 32x32 -> 16x16, fused GAP. 4 pixel tiles x 64 n x 4 k
    // (SWAPYZ: kb-partners 256 apart in linear id -> same XCD)
    conv_mfma<256, 32, 32, 512, 64, true, true>
        <<<dim3(4, 64, 4), 256, 0, stream>>>(h2, A3, b3, zguard, pooled);

    fc1_kernel<<<256, 256, 0, stream>>>(pooled, fwm1, fb1, fc1h);
    fc2_kernel<<<64, 256, 0, stream>>>(fc1h, fwm2, fb2, out);
}

// Round 8
// 439.752 us; speedup vs baseline: 1.3517x; 1.0104x over previous
//
#include <hip/hip_runtime.h>
#include <stdint.h>

// ---------------------------------------------------------------------------
// Net_27891517620298: edge-popup supermask CNN forward.
// R25: R24 + VMEM-ordering fix. R24's counted-vmcnt overlap was defeated by
// in-order vmcnt retirement: per-tap A-loads were issued AFTER the stage
// DMAs, so tap 0's A-wait (newest load) forced ALL older stage DMAs to
// retire -> stage and taps still serialized (conv3 stuck at 106us, bank
// conflicts 0 proving the layout itself was fine). Fix: per chunk, issue all
// 18 A-frag loads FIRST (af[9][2], fully-unrolled static indexing ->
// registers), then the async stage DMAs, with sched_barrier(0) fences
// pinning the order (the piece R19 lacked). The compiler's af-waits become
// counted vmcnt(N>=stage-outstanding): stage drains under the taps.
// Only vmcnt(0) is at chunk end, after all compute.
// Signature to verify: VGPR ~68 -> ~150 (pipeline materialized).
// ---------------------------------------------------------------------------

typedef __attribute__((ext_vector_type(8))) short short8;
typedef __attribute__((ext_vector_type(4))) short short4v;
typedef __attribute__((ext_vector_type(4))) float floatx4;

__device__ __forceinline__ unsigned short f2bf(float f) {
    unsigned u = __float_as_uint(f);
    u += 0x7fffu + ((u >> 16) & 1u);   // round-to-nearest-even
    return (unsigned short)(u >> 16);
}

// async global->LDS DMA, 16B/lane; LDS dest = wave-uniform base + lane*16
__device__ __forceinline__ void stage16(const unsigned short* g, unsigned short* l) {
    __builtin_amdgcn_global_load_lds(
        (const __attribute__((address_space(1))) unsigned int*)(const void*)g,
        (__attribute__((address_space(3))) unsigned int*)(void*)l,
        16, 0, 0);
}

// ---------------- exact top-k selection: 3-pass 11/11/9-bit radix -----------
constexpr unsigned CUM0 = 3456u;
constexpr unsigned CUM1 = 298368u;
constexpr unsigned CUM2 = 1478016u;
constexpr unsigned CUM3 = 2002304u;
constexpr unsigned STOT = 2012544u;
constexpr int NBH = 512;

__device__ __forceinline__ int find_tensor(unsigned idx, unsigned& li) {
    if (idx < CUM0) { li = idx;        return 0; }
    if (idx < CUM1) { li = idx - CUM0; return 1; }
    if (idx < CUM2) { li = idx - CUM1; return 2; }
    if (idx < CUM3) { li = idx - CUM2; return 3; }
    li = idx - CUM3; return 4;
}

__global__ __launch_bounds__(256) void hist11(const float* __restrict__ s0,
                                              const float* __restrict__ s1,
                                              const float* __restrict__ s2,
                                              const float* __restrict__ s3,
                                              const float* __restrict__ s4,
                                              const unsigned* __restrict__ P,
                                              unsigned* __restrict__ ghist, int pass) {
    __shared__ unsigned lh[10240];
    const int tid = threadIdx.x;
    const int NB = (pass == 2) ? 512 : 2048;
    for (int i = tid; i < NB * 5; i += 256) lh[i] = 0;
    __syncthreads();

    unsigned pref[5];
    #pragma unroll
    for (int t = 0; t < 5; t++) pref[t] = pass ? P[t] : 0u;
    const int fsh = (pass == 1) ? 20 : 9;

    for (unsigned idx = blockIdx.x * 256u + tid; idx < STOT; idx += NBH * 256u) {
        unsigned li; int t = find_tensor(idx, li);
        const float* sp = t == 0 ? s0 : t == 1 ? s1 : t == 2 ? s2 : t == 3 ? s3 : s4;
        unsigned key = __float_as_uint(sp[li]) & 0x7fffffffu;
        bool ok = (pass == 0) || ((key >> fsh) == pref[t]);
        if (ok) {
            unsigned bin = (pass == 0) ? (key >> 20)
                         : (pass == 1) ? ((key >> 9) & 2047u)
                                       : (key & 511u);
            atomicAdd(&lh[(unsigned)t * NB + bin], 1u);
        }
    }
    __syncthreads();
    const int goff = (pass == 0) ? 0 : (pass == 1) ? 10240 : 20480;
    for (int i = tid; i < NB * 5; i += 256) {
        unsigned v = lh[i];
        if (v) atomicAdd(&ghist[goff + i], v);
    }
}

__global__ __launch_bounds__(256) void find11(const unsigned* __restrict__ ghist,
                                              unsigned* __restrict__ P,
                                              unsigned* __restrict__ targ, int pass) {
    const int t = blockIdx.x;
    const int tid = threadIdx.x;
    const int NB = (pass == 2) ? 512 : 2048;
    const int goff = (pass == 0) ? 0 : (pass == 1) ? 10240 : 20480;
    const int seg = NB / 256;
    __shared__ unsigned bins[2048];
    __shared__ unsigned part[256];
    for (int i = tid; i < NB; i += 256) bins[i] = ghist[goff + t * NB + i];
    __syncthreads();
    unsigned s = 0;
    for (int j = 0; j < seg; j++) s += bins[tid * seg + j];
    part[tid] = s;
    __syncthreads();
    if (tid == 0) {
        unsigned n = t == 0 ? 3456u : t == 1 ? 294912u : t == 2 ? 1179648u
                   : t == 3 ? 524288u : 10240u;
        unsigned target = (pass == 0) ? (n >> 1) : targ[t];
        unsigned cum = 0; int q = 0;
        for (; q < 256; q++) { unsigned c = part[q]; if (cum + c > target) break; cum += c; }
        int b = q * seg;
        for (;; b++) { unsigned c = bins[b]; if (cum + c > target) break; cum += c; }
        targ[t] = target - cum;
        if (pass == 0)      P[t] = (unsigned)b;
        else if (pass == 1) P[t] = (P[t] << 11) | (unsigned)b;
        else                P[t] = (P[t] << 9) | (unsigned)b;
    }
}

__global__ void mask_reorder(const float* __restrict__ w0, const float* __restrict__ w1,
                             const float* __restrict__ w2, const float* __restrict__ w3,
                             const float* __restrict__ w4,
                             const float* __restrict__ s0, const float* __restrict__ s1,
                             const float* __restrict__ s2, const float* __restrict__ s3,
                             const float* __restrict__ s4,
                             const unsigned* __restrict__ T,
                             float* __restrict__ wm1,
                             unsigned short* __restrict__ A2,
                             unsigned short* __restrict__ A3,
                             float* __restrict__ fwm1, float* __restrict__ fwm2,
                             float* __restrict__ pooled) {
    unsigned idx = blockIdx.x * 256u + threadIdx.x;
    if (idx >= STOT) return;
    if (idx < 32768u) pooled[idx] = 0.f;
    unsigned li; int t = find_tensor(idx, li);
    const float* sp = t == 0 ? s0 : t == 1 ? s1 : t == 2 ? s2 : t == 3 ? s3 : s4;
    const float* wp = t == 0 ? w0 : t == 1 ? w1 : t == 2 ? w2 : t == 3 ? w3 : w4;
    unsigned key = __float_as_uint(sp[li]) & 0x7fffffffu;
    float val = (key >= T[t]) ? wp[li] : 0.f;
    if (t == 0) {
        wm1[li] = val;
    } else if (t == 1) {           // w2 [256][128][3][3] -> A2 [e][256][128]
        unsigned k = li / 1152u, r = li - k * 1152u;
        unsigned c = r / 9u, e = r - c * 9u;
        A2[((size_t)e * 256u + k) * 128u + c] = f2bf(val);
    } else if (t == 2) {           // w3 [512][256][3][3] -> A3 [e][512][256]
        unsigned k = li / 2304u, r = li - k * 2304u;
        unsigned c = r / 9u, e = r - c * 9u;
        A3[((size_t)e * 512u + k) * 256u + c] = f2bf(val);
    } else if (t == 3) {
        fwm1[li] = val;
    } else {
        fwm2[li] = val;
    }
}

// ---------------- conv1: direct 3x3 fp32 -> bf16 NHWC -----------------------
template <int C, int H, int W, int K, int TX, int TY, int KT>
__global__ __launch_bounds__(TX* TY) void conv_direct(const float* __restrict__ in,
                                                      const float* __restrict__ wm,
                                                      const float* __restrict__ bias,
                                                      unsigned short* __restrict__ out) {
    constexpr int TILW = TX * 2, TILH = TY * 2;
    constexpr int ITW = TILW + 2, ITH = TILH + 2;
    constexpr int NTHREADS = TX * TY;
    constexpr int NLOAD = (ITH * ITW + NTHREADS - 1) / NTHREADS;
    constexpr int KG = K / KT;

    __shared__ float sIn[ITH * ITW];
    __shared__ float sW[9 * KT];

    const int tid = threadIdx.x;
    const int tx = tid % TX, ty = tid / TX;
    const int kg = blockIdx.z % KG, n = blockIdx.z / KG;
    const int ox0 = blockIdx.x * TILW, oy0 = blockIdx.y * TILH;
    const int ix0 = ox0 - 1, iy0 = oy0 - 1;

    const float* inN = in + (size_t)n * C * H * W;
    const float* wkg = wm + (size_t)kg * KT * C * 9;

    int goff[NLOAD];
    #pragma unroll
    for (int i = 0; i < NLOAD; i++) {
        int idx = tid + i * NTHREADS;
        if (idx < ITH * ITW) {
            int r = idx / ITW, col = idx % ITW;
            int gy = iy0 + r, gx = ix0 + col;
            goff[i] = (gy >= 0 && gy < H && gx >= 0 && gx < W) ? (gy * W + gx) : -1;
        } else goff[i] = -2;
    }

    float acc[2][2][KT];
    #pragma unroll
    for (int py = 0; py < 2; py++)
        #pragma unroll
        for (int px = 0; px < 2; px++)
            #pragma unroll
            for (int j = 0; j < KT; j++) acc[py][px][j] = 0.f;

    for (int c = 0; c < C; c++) {
        const float* inC = inN + (size_t)c * H * W;
        #pragma unroll
        for (int i = 0; i < NLOAD; i++) {
            int g = goff[i];
            if (g >= -1) sIn[tid + i * NTHREADS] = (g >= 0) ? inC[g] : 0.f;
        }
        for (int i = tid; i < 9 * KT; i += NTHREADS) {
            int e = i / KT, j = i % KT;
            sW[i] = wkg[j * C * 9 + c * 9 + e];
        }
        __syncthreads();

        float vin[4][4];
        const float* base = &sIn[(ty * 2) * ITW + tx * 2];
        #pragma unroll
        for (int r = 0; r < 4; r++)
            #pragma unroll
            for (int cc = 0; cc < 4; cc++) vin[r][cc] = base[r * ITW + cc];

        #pragma unroll
        for (int e = 0; e < 9; e++) {
            const int dy = e / 3, dx = e % 3;
            #pragma unroll
            for (int j = 0; j < KT; j++) {
                float wv = sW[e * KT + j];
                #pragma unroll
                for (int py = 0; py < 2; py++)
                    #pragma unroll
                    for (int px = 0; px < 2; px++)
                        acc[py][px][j] = fmaf(vin[py + dy][px + dx], wv, acc[py][px][j]);
            }
        }
        __syncthreads();
    }

    float bj[KT];
    #pragma unroll
    for (int j = 0; j < KT; j++) bj[j] = bias[kg * KT + j];
    #pragma unroll
    for (int py = 0; py < 2; py++)
        #pragma unroll
        for (int px = 0; px < 2; px++) {
            int oy = oy0 + ty * 2 + py, ox = ox0 + tx * 2 + px;
            short8 v;
            #pragma unroll
            for (int j = 0; j < KT; j++) {
                float t = acc[py][px][j] + bj[j];
                v[j] = (short)f2bf(t > 0.f ? t : 0.f);
            }
            *(short8*)(out + ((size_t)(n * H + oy) * W + ox) * K + kg * KT) = v;
        }
}

// ---------------- conv2/conv3: NHWC MFMA, dbuf async B, A-first order -------
// stride-2 3x3 conv, bf16 NHWC input. Block = 4 waves; tile 128k x NPIX pix.
// LDS per buffer: pixel p -> 5 16B slots (4 channel quads + pad, never read);
// linear slot order = global_load_lds dest; tap reads = R17 PSTR=40 addrs.
// Chunk: A-loads(18, oldest) -> SGB -> stage next (async DMA, newest) -> SGB
// -> 9 unrolled taps (af waits = counted vmcnt, stage stays in flight)
// -> vmcnt(0) -> s_barrier.
template <int C, int H, int W, int KOUT, int NPIX, bool POOL, bool SWAPYZ>
__global__ __launch_bounds__(256, 2) void conv_mfma(const unsigned short* __restrict__ in,
                                                    const unsigned short* __restrict__ A,
                                                    const float* __restrict__ bias,
                                                    const unsigned short* __restrict__ zg,
                                                    void* __restrict__ outv) {
    constexpr int OH = H / 2, OW = W / 2;
    constexpr int PR = NPIX / OW;          // output rows per pixel tile
    constexpr int FN = NPIX / 16;          // B-frags per wave
    constexpr int RH = 2 * PR + 1;         // input rows needed
    constexpr int IW = W + 1;              // input cols needed
    constexpr int NC = C / 32;
    constexpr int NPT = RH * IW;           // tile pixels
    constexpr int NSLOT = NPT * 5;         // 5 16B-slots per pixel (4 + pad)
    constexpr int SLMAX = (NSLOT + 255) / 256;
    constexpr int SLOTS = SLMAX * 256;     // padded slot count

    __shared__ unsigned short sIn[2][SLOTS * 8];

    const int tid = threadIdx.x;
    const int lane = tid & 63;
    const int wv = tid >> 6;
    const int l15 = lane & 15;
    const int quad = lane >> 4;
    const int pt = blockIdx.x;
    const int kb = SWAPYZ ? blockIdx.z : blockIdx.y;
    const int n  = SWAPYZ ? blockIdx.y : blockIdx.z;
    const int k0 = kb * 128;
    const int oy0 = pt * PR;
    const int g0y = 2 * oy0 - 1;
    const int mw = wv * 32;                // wave's 32 output-channel rows

    // staging source table (chunk-invariant): slot s = tid + i*256 ->
    // pixel s/5, sub-slot s%5; sub-slot 4 and OOB pixels stage from zguard.
    int goff[SLMAX];
    #pragma unroll
    for (int i = 0; i < SLMAX; i++) {
        int s = tid + i * 256;
        int pix = s / 5, q = s - pix * 5;
        int iy = pix / IW, ix = pix - iy * IW;
        int gy = g0y + iy, gx = ix - 1;
        bool ok = (s < NSLOT) && (q < 4) && (gy >= 0) && (gy < H) && (gx >= 0);
        goff[i] = ok ? ((gy * W + gx) * C + q * 8) : -1;
    }

    // B-frag pixel bases (shorts): identical to R17 PSTR=40 addressing
    int pB[FN];
    #pragma unroll
    for (int fn = 0; fn < FN; fn++) {
        int p = fn * 16 + l15;
        int oyl = p / OW, oxl = p % OW;
        pB[fn] = (oyl * 2 * IW + oxl * 2) * 40 + quad * 8;
    }

    const unsigned short* inN = in + (size_t)n * H * W * C;

    floatx4 acc[2][FN];
    #pragma unroll
    for (int fm = 0; fm < 2; fm++)
        #pragma unroll
        for (int fn = 0; fn < FN; fn++) acc[fm][fn] = (floatx4){0.f, 0.f, 0.f, 0.f};

    const size_t estr = (size_t)KOUT * C;
    const int wvb = tid & 192;             // wave-uniform lane-0 slot offset

    auto stage_chunk = [&](int buf, int cc) {
        const int cof = cc * 32;
        #pragma unroll
        for (int i = 0; i < SLMAX; i++) {
            const unsigned short* src = (goff[i] >= 0) ? (inN + goff[i] + cof) : zg;
            stage16(src, &sIn[buf][(size_t)(i * 256 + wvb) * 8]);
        }
    };

    // prologue: chunk 0 staged and drained once
    stage_chunk(0, 0);
    asm volatile("s_waitcnt vmcnt(0)" ::: "memory");
    __builtin_amdgcn_s_barrier();
    __builtin_amdgcn_sched_barrier(0);

    #pragma unroll 1
    for (int cc = 0; cc < NC; cc++) {
        const int cur = cc & 1;
        const unsigned short* sb = &sIn[cur][0];

        // (1) ALL A-frag loads first -> OLDEST in the vmcnt queue. Static
        // indexing (full unroll below) keeps af[][] in registers.
        const unsigned short* Abase = A + (size_t)(k0 + mw + l15) * C + cc * 32 + quad * 8;
        short8 af[9][2];
        #pragma unroll
        for (int e = 0; e < 9; e++) {
            af[e][0] = *(const short8*)(Abase + (size_t)e * estr);
            af[e][1] = *(const short8*)(Abase + (size_t)e * estr + 16 * C);
        }
        __builtin_amdgcn_sched_barrier(0);   // pin: A-loads stay above stage

        // (2) stage next chunk (async DMA, NEWEST -> af waits don't drain it)
        if (cc + 1 < NC) stage_chunk(cur ^ 1, cc + 1);
        __builtin_amdgcn_sched_barrier(0);   // pin: stage stays above taps

        // (3) 9 taps, fully unrolled: ds_read + MFMA; af waits are counted
        #pragma unroll
        for (int e = 0; e < 9; e++) {
            const int dy = e / 3, dx = e - dy * 3;
            const int boff = (dy * IW + dx) * 40;
            short8 bfr[FN];
            #pragma unroll
            for (int fn = 0; fn < FN; fn++)
                bfr[fn] = *(const short8*)(sb + pB[fn] + boff);
            #pragma unroll
            for (int fn = 0; fn < FN; fn++) {
                acc[0][fn] = __builtin_amdgcn_mfma_f32_16x16x32_bf16(af[e][0], bfr[fn], acc[0][fn], 0, 0, 0);
                acc[1][fn] = __builtin_amdgcn_mfma_f32_16x16x32_bf16(af[e][1], bfr[fn], acc[1][fn], 0, 0, 0);
            }
        }

        // (4) next chunk's stage has drained under the taps; sync buffers
        asm volatile("s_waitcnt vmcnt(0)" ::: "memory");
        __builtin_amdgcn_s_barrier();
        __builtin_amdgcn_sched_barrier(0);
    }

    if (!POOL) {
        unsigned short* out = (unsigned short*)outv;
        #pragma unroll
        for (int fm = 0; fm < 2; fm++) {
            const int k4 = k0 + mw + fm * 16 + quad * 4;
            float b0 = bias[k4], b1 = bias[k4 + 1], b2 = bias[k4 + 2], b3 = bias[k4 + 3];
            #pragma unroll
            for (int fn = 0; fn < FN; fn++) {
                int p = fn * 16 + l15;
                int oy = oy0 + p / OW, ox = p % OW;
                float v0 = acc[fm][fn][0] + b0, v1 = acc[fm][fn][1] + b1;
                float v2 = acc[fm][fn][2] + b2, v3 = acc[fm][fn][3] + b3;
                short4v v;
                v[0] = (short)f2bf(v0 > 0.f ? v0 : 0.f);
                v[1] = (short)f2bf(v1 > 0.f ? v1 : 0.f);
                v[2] = (short)f2bf(v2 > 0.f ? v2 : 0.f);
                v[3] = (short)f2bf(v3 > 0.f ? v3 : 0.f);
                *(short4v*)(out + ((size_t)(n * OH + oy) * OW + ox) * KOUT + k4) = v;
            }
        }
    } else {
        float* out = (float*)outv;
        #pragma unroll
        for (int fm = 0; fm < 2; fm++) {
            #pragma unroll
            for (int reg = 0; reg < 4; reg++) {
                int k = k0 + mw + fm * 16 + quad * 4 + reg;
                float bv = bias[k];
                float s = 0.f;
                #pragma unroll
                for (int fn = 0; fn < FN; fn++) {
                    float v = acc[fm][fn][reg] + bv;
                    s += v > 0.f ? v : 0.f;
                }
                s += __shfl_xor(s, 1); s += __shfl_xor(s, 2);
                s += __shfl_xor(s, 4); s += __shfl_xor(s, 8);
                if (l15 == 0) atomicAdd(&out[n * KOUT + k], s * (1.0f / (OH * OW)));
            }
        }
    }
}

// ---------------- FCs (fp32, tiny; R9 versions) -----------------------------
__global__ void fc1_kernel(const float* __restrict__ pooled, const float* __restrict__ w,
                           const float* __restrict__ b, float* __restrict__ out) {
    int t = blockIdx.x * 256 + threadIdx.x;
    int o = t & 1023, n = t >> 10;
    const float4* w4 = (const float4*)(w + (size_t)o * 512);
    const float4* p4 = (const float4*)(pooled + (size_t)n * 512);
    float acc = 0.f;
    for (int i = 0; i < 128; i++) {
        float4 a = p4[i], ww = w4[i];
        acc += a.x * ww.x + a.y * ww.y + a.z * ww.z + a.w * ww.w;
    }
    acc += b[o];
    out[t] = acc > 0.f ? acc : 0.f;
}

__global__ void fc2_kernel(const float* __restrict__ h, const float* __restrict__ w,
                           const float* __restrict__ b, float* __restrict__ out) {
    int n = blockIdx.x, tid = threadIdx.x;
    __shared__ float redw[40];
    const float4* h4 = (const float4*)(h + (size_t)n * 1024);
    float4 a = h4[tid];
    for (int o = 0; o < 10; o++) {
        const float4* w4 = (const float4*)(w + (size_t)o * 1024);
        float4 ww = w4[tid];
        float v = a.x * ww.x + a.y * ww.y + a.z * ww.z + a.w * ww.w;
        for (int off = 32; off > 0; off >>= 1) v += __shfl_down(v, off);
        if ((tid & 63) == 0) redw[o * 4 + (tid >> 6)] = v;
    }
    __syncthreads();
    if (tid < 10) {
        float s = redw[tid * 4] + redw[tid * 4 + 1] + redw[tid * 4 + 2] + redw[tid * 4 + 3] + b[tid];
        out[n * 10 + tid] = s;
    }
}

extern "C" void kernel_launch(void* const* d_in, const int* in_sizes, int n_in,
                              void* d_out, int out_size, void* d_ws, size_t ws_size,
                              hipStream_t stream) {
    const float* x   = (const float*)d_in[0];
    const float* w1  = (const float*)d_in[1];
    const float* s1  = (const float*)d_in[2];
    const float* b1  = (const float*)d_in[3];
    const float* w2  = (const float*)d_in[4];
    const float* s2  = (const float*)d_in[5];
    const float* b2  = (const float*)d_in[6];
    const float* w3  = (const float*)d_in[7];
    const float* s3  = (const float*)d_in[8];
    const float* b3  = (const float*)d_in[9];
    const float* fw1 = (const float*)d_in[10];
    const float* fs1 = (const float*)d_in[11];
    const float* fb1 = (const float*)d_in[12];
    const float* fw2 = (const float*)d_in[13];
    const float* fs2 = (const float*)d_in[14];
    const float* fb2 = (const float*)d_in[15];
    float* out = (float*)d_out;

    char* ws = (char*)d_ws;
    size_t off = 0;
    auto alloc = [&](size_t bytes) -> char* {
        char* p = ws + off;
        off = (off + bytes + 255) & ~(size_t)255;
        return p;
    };
    unsigned* ghist = (unsigned*)alloc(23040ull * 4);
    unsigned short* zguard = (unsigned short*)alloc(256);  // zeros, after ghist
    unsigned* P     = (unsigned*)alloc(64);
    unsigned* targ  = (unsigned*)alloc(64);
    float* wm1  = (float*)alloc(3456ull * 4);
    float* fwm1 = (float*)alloc(524288ull * 4);
    float* fwm2 = (float*)alloc(10240ull * 4);
    unsigned short* A2 = (unsigned short*)alloc(294912ull * 2);   // bf16 [9][256][128]
    unsigned short* A3 = (unsigned short*)alloc(1179648ull * 2);  // bf16 [9][512][256]
    unsigned short* h1 = (unsigned short*)alloc(33554432ull * 2); // bf16 NHWC 64x64x64x128
    unsigned short* h2 = (unsigned short*)alloc(16777216ull * 2); // bf16 NHWC 64x32x32x256
    float* pooled = (float*)alloc(32768ull * 4);                  // 64x512
    float* fc1h   = (float*)alloc(65536ull * 4);                  // 64x1024
    if (off > ws_size) return;

    // one memset covers ghist (92160 B) + zguard (256 B) - contiguous
    (void)hipMemsetAsync(ghist, 0, 23040ull * 4 + 256, stream);

    for (int pass = 0; pass < 3; pass++) {
        hist11<<<NBH, 256, 0, stream>>>(s1, s2, s3, fs1, fs2, P, ghist, pass);
        find11<<<5, 256, 0, stream>>>(ghist, P, targ, pass);
    }
    int gs = (STOT + 255) / 256;
    mask_reorder<<<gs, 256, 0, stream>>>(w1, w2, w3, fw1, fw2, s1, s2, s3, fs1, fs2, P,
                                         wm1, A2, A3, fwm1, fwm2, pooled);

    // conv1: 3->128, 64x64, stride 1, direct fp32 -> bf16 NHWC h1
    conv_direct<3, 64, 64, 128, 16, 16, 8>
        <<<dim3(2, 2, 64 * 16), 256, 0, stream>>>(x, wm1, b1, h1);
    // conv2: 128->256, 64x64 -> 32x32 NHWC. 16 pixel tiles x 2 k tiles x 64 n
    conv_mfma<128, 64, 64, 256, 64, false, false>
        <<<dim3(16, 2, 64), 256, 0, stream>>>(h1, A2, b2, zguard, h2);
    // conv3: 256->512, 32x32 -> 16x16, fused GAP. 4 pixel tiles x 64 n x 4 k
    // (SWAPYZ: kb-partners 256 apart in linear id -> same XCD)
    conv_mfma<256, 32, 32, 512, 64, true, true>
        <<<dim3(4, 64, 4), 256, 0, stream>>>(h2, A3, b3, zguard, pooled);

    fc1_kernel<<<256, 256, 0, stream>>>(pooled, fwm1, fb1, fc1h);
    fc2_kernel<<<64, 256, 0, stream>>>(fc1h, fwm2, fb2, out);
}